// Round 3
// baseline (258.963 us; speedup 1.0000x reference)
//
#include <hip/hip_runtime.h>

#define L 4096
#define NT 256
#define PER (L / NT)          // 16 elements per thread
#define MD 32                 // MIN_DIST
#define TILE 32
#define NTILES (L / TILE)     // 128
#define TS 33                 // padded tile stride (u64 elems) to break bank conflicts

typedef unsigned long long u64;

// One block per row. Exact greedy NMS via iterative local-max peeling.
// Windowed max via van Herk: W[i] = max(sfx[i-32], T[tile(i)], pfx[i+32]).
// Composite key (distinct across i): (1<<44) | (bits(|x|)<<12) | (4095-i)
// so descending-key order == JAX stable argsort(-|x|) order.
__global__ __launch_bounds__(NT) void extrema_nms_kernel(const float* __restrict__ in,
                                                         float* __restrict__ out) {
    __shared__ float xs[L];
    __shared__ u64 Kp[NTILES * TS];            // keys, 33-stride per 32-tile
    __shared__ u64 pfxA[(NTILES + 2) * TS];    // tiles -1..128 (pad tiles zero)
    __shared__ u64 sfxA[(NTILES + 2) * TS];
    __shared__ u64 TA[NTILES + 2];             // tile aggregates, pads zero
    __shared__ unsigned int keptbits[L / 32];
    __shared__ int flags[2];

    const int tid = threadIdx.x;
    const float* x = in + (size_t)blockIdx.x * L;

    // ---- load row + zero pads/flags ----
    #pragma unroll
    for (int k = 0; k < PER; ++k) xs[tid + k * NT] = x[tid + k * NT];
    if (tid < TS) {
        pfxA[tid] = 0; sfxA[tid] = 0;                        // front pad tile
        pfxA[(NTILES + 1) * TS + tid] = 0;                   // back pad tile
        sfxA[(NTILES + 1) * TS + tid] = 0;
    }
    if (tid < L / 32) keptbits[tid] = 0u;
    if (tid == 0) { TA[0] = 0; TA[NTILES + 1] = 0; flags[0] = 0; flags[1] = 0; }
    __syncthreads();

    // ---- extrema mask -> sortable composite key ----
    // right[i] = (i<L-1) && x[i+1] >  x[i]   (end pad => False at L-1)
    // left[i]  = (i==0)  || x[i]   <= x[i-1] (front pad => True at 0)
    // valley = right & left & (x<=0) ; peak = !right & !left & (x>0)
    #pragma unroll
    for (int k = 0; k < PER; ++k) {
        int i = tid + k * NT;
        float xi = xs[i];
        bool right = (i < L - 1) && (xs[i + 1] > xi);
        bool left  = (i == 0) || (xi <= xs[i - 1]);
        bool neg   = (xi <= 0.0f);
        bool ext = (right && left && neg) || (!right && !left && !neg);
        u64 key = 0;
        if (ext) {
            unsigned int ab = __float_as_uint(xi) & 0x7fffffffu;
            key = (1ULL << 44) | ((u64)ab << 12) | (u64)(L - 1 - i);
        }
        Kp[i + (i >> 5)] = key;
    }
    __syncthreads();

    // ---- peeling rounds (exact greedy NMS fixpoint), 2 barriers/round ----
    for (int r = 0; r < 300; ++r) {
        // phase 1: per-32-tile prefix/suffix max (2 threads per tile)
        {
            const int tile = tid >> 1;
            const u64* src = &Kp[tile * TS];
            u64 v[TILE];
            #pragma unroll
            for (int c = 0; c < TILE; ++c) v[c] = src[c];
            if (tid & 1) {
                #pragma unroll
                for (int c = TILE - 2; c >= 0; --c) if (v[c + 1] > v[c]) v[c] = v[c + 1];
                u64* dst = &sfxA[(tile + 1) * TS];
                #pragma unroll
                for (int c = 0; c < TILE; ++c) dst[c] = v[c];
                TA[tile + 1] = v[0];                         // tile max
            } else {
                #pragma unroll
                for (int c = 1; c < TILE; ++c) if (v[c - 1] > v[c]) v[c] = v[c - 1];
                u64* dst = &pfxA[(tile + 1) * TS];
                #pragma unroll
                for (int c = 0; c < TILE; ++c) dst[c] = v[c];
            }
        }
        __syncthreads();

        // phase 2: winner detect + suppress (merged; snapshot makes it exact)
        {
            if (tid == 0) flags[(r + 1) & 1] = 0;            // reset other-parity flag
            bool won = false;
            #pragma unroll
            for (int k = 0; k < PER; ++k) {
                int i = tid + k * NT;
                u64 Ki = Kp[i + (i >> 5)];
                if (!Ki) continue;
                int t = i >> 5, o = i & 31;
                u64 W = sfxA[t * TS + o];                    // [i-32 .. tile end]
                u64 w2 = TA[t + 1];      if (w2 > W) W = w2; // full tile t
                u64 w3 = pfxA[(t + 2) * TS + o]; if (w3 > W) W = w3; // [.. i+32]
                if (W == Ki) {                               // strict window max
                    won = true;
                    atomicOr(&keptbits[i >> 5], 1u << (i & 31));
                    int lo = i - MD; if (lo < 0) lo = 0;
                    int hi = i + MD; if (hi > L - 1) hi = L - 1;
                    for (int j = lo; j <= hi; ++j) Kp[j + (j >> 5)] = 0; // benign races
                }
            }
            if (won) flags[r & 1] = 1;                       // same-value race benign
        }
        __syncthreads();
        if (!flags[r & 1]) break;                            // uniform read
    }

    // ---- output ----
    #pragma unroll
    for (int k = 0; k < PER; ++k) {
        int i = tid + k * NT;
        bool kept = (keptbits[i >> 5] >> (i & 31)) & 1u;
        out[(size_t)blockIdx.x * L + i] = kept ? xs[i] : 0.0f;
    }
}

extern "C" void kernel_launch(void* const* d_in, const int* in_sizes, int n_in,
                              void* d_out, int out_size, void* d_ws, size_t ws_size,
                              hipStream_t stream) {
    const float* in = (const float*)d_in[0];
    float* out = (float*)d_out;
    int rows = in_sizes[0] / L;   // 128
    extrema_nms_kernel<<<rows, NT, 0, stream>>>(in, out);
}

// Round 4
// 20.368 us; speedup vs baseline: 12.7141x; 12.7141x over previous
//
#include <hip/hip_runtime.h>

#define L 4096
#define NT 256
#define C 16                  // elements per thread (one chunk per thread)
#define MD 32                 // MIN_DIST
#define TS 17                 // padded u64 stride per chunk row (bank-conflict break)
#define PADC 2                // pad chunks on each side

typedef unsigned long long u64;

// One block per row. Exact greedy NMS via iterative local-max peeling.
// Keys live in registers (thread t owns elements [16t, 16t+16)).
// Windowed max (chunk=16): W(i) = max(sfx[c-2][o], T[c-1], T[c], T[c+1], pfx[c+2][o])
// which exactly covers [i-32, i+32] clipped. Composite key (distinct):
// (1<<44) | (bits(|x|)<<12) | (4095-i)  => descending order == stable argsort(-|x|).
__global__ __launch_bounds__(NT) void extrema_nms_kernel(const float* __restrict__ in,
                                                         float* __restrict__ out) {
    __shared__ u64 sfx[(NT + 2 * PADC) * TS];
    __shared__ u64 pfx[(NT + 2 * PADC) * TS];
    __shared__ u64 TA[NT + 2 * PADC];
    __shared__ unsigned int winm[NT + 2 * PADC];
    __shared__ int flags[2];

    const int tid = threadIdx.x;
    const int cc = tid + PADC;                   // padded chunk index
    const int base = tid * C;                    // first global element of my chunk
    const float* xrow = in + (size_t)blockIdx.x * L;

    // ---- zero pads (written once; never touched again) ----
    if (tid < PADC * TS) {
        sfx[tid] = 0; pfx[tid] = 0;
        sfx[(NT + PADC) * TS + tid] = 0;
        pfx[(NT + PADC) * TS + tid] = 0;
    }
    if (tid < PADC) {
        TA[tid] = 0; TA[NT + PADC + tid] = 0;
        winm[tid] = 0; winm[NT + PADC + tid] = 0;
    }
    if (tid == 0) { flags[0] = 0; flags[1] = 0; }

    // ---- load own 16 x values + boundary neighbors ----
    float xv[C];
    #pragma unroll
    for (int k = 0; k < C; k += 4) {
        float4 f = *reinterpret_cast<const float4*>(xrow + base + k);
        xv[k] = f.x; xv[k + 1] = f.y; xv[k + 2] = f.z; xv[k + 3] = f.w;
    }
    float xl = (base > 0) ? xrow[base - 1] : 0.0f;       // unused value when base==0
    float xr = (base + C < L) ? xrow[base + C] : 0.0f;   // unused value when at end

    // ---- extrema mask -> keys (in registers) ----
    // right[i] = (i<L-1) && x[i+1] >  x[i]   (end pad => False at L-1)
    // left[i]  = (i==0)  || x[i]   <= x[i-1] (front pad => True at 0)
    u64 key[C];
    #pragma unroll
    for (int o = 0; o < C; ++o) {
        int i = base + o;
        float xi = xv[o];
        float xp = (o == 0) ? xl : xv[o - 1];
        float xn = (o == C - 1) ? xr : xv[o + 1];
        bool right = (i < L - 1) && (xn > xi);
        bool left  = (i == 0) || (xi <= xp);
        bool neg   = (xi <= 0.0f);
        bool ext = (right && left && neg) || (!right && !left && !neg);
        u64 kk = 0;
        if (ext) {
            unsigned int ab = __float_as_uint(xi) & 0x7fffffffu;
            kk = (1ULL << 44) | ((u64)ab << 12) | (u64)(L - 1 - i);
        }
        key[o] = kk;
    }

    unsigned int keptm = 0;

    // ---- peeling rounds: 2 barriers per round ----
    for (int r = 0; r < 300; ++r) {
        // ===== F phase: suppress from last round's winners, then scans =====
        if (r > 0) {
            int any = flags[(r - 1) & 1];
            if (tid == 0) flags[r & 1] = 0;      // slot ph2(r) will set; safe (2 barriers from last read)
            if (!any) break;                      // uniform: fixpoint reached
            // 80-bit winner window across chunks cc-2..cc+2
            unsigned int m0 = winm[cc - 2], m1 = winm[cc - 1], m2 = winm[cc];
            unsigned int m3 = winm[cc + 1], m4 = winm[cc + 2];
            u64 W0 = (u64)(m0 & 0xffffu) | ((u64)(m1 & 0xffffu) << 16)
                   | ((u64)(m2 & 0xffffu) << 32) | ((u64)(m3 & 0xffffu) << 48);
            u64 W1 = (u64)(m4 & 0xffffu);
            if (W0 | W1) {
                #pragma unroll
                for (int o = 0; o < C; ++o) {
                    // suppressed iff any winner bit in window bits [o, o+64]
                    bool sup = ((W0 >> o) != 0ULL) || ((W1 & ((2ULL << o) - 1ULL)) != 0ULL);
                    if (sup) key[o] = 0;
                }
            }
        }
        {   // in-register scans -> LDS (static indices only; no spill)
            u64 run = 0;
            u64 pf[C];
            #pragma unroll
            for (int o = 0; o < C; ++o) { u64 kk = key[o]; if (kk > run) run = kk; pf[o] = run; }
            u64* dp = &pfx[cc * TS];
            #pragma unroll
            for (int o = 0; o < C; ++o) dp[o] = pf[o];
            TA[cc] = run;                         // chunk max
            u64 run2 = 0;
            u64 sf[C];
            #pragma unroll
            for (int o = C - 1; o >= 0; --o) { u64 kk = key[o]; if (kk > run2) run2 = kk; sf[o] = run2; }
            u64* sp = &sfx[cc * TS];
            #pragma unroll
            for (int o = 0; o < C; ++o) sp[o] = sf[o];
        }
        __syncthreads();

        // ===== detect phase: winner = strict max in own +-32 window =====
        {
            u64 t0 = TA[cc - 1], t1 = TA[cc], t2 = TA[cc + 1];
            u64 tmax = (t0 > t1) ? t0 : t1; if (t2 > tmax) tmax = t2;
            const u64* sp = &sfx[(cc - 2) * TS];
            const u64* pp = &pfx[(cc + 2) * TS];
            unsigned int wm = 0;
            #pragma unroll
            for (int o = 0; o < C; ++o) {
                u64 kk = key[o];
                if (kk) {
                    u64 W = sp[o]; if (tmax > W) W = tmax;
                    u64 p2 = pp[o]; if (p2 > W) W = p2;
                    if (W == kk) wm |= (1u << o);
                }
            }
            winm[cc] = wm;                        // unconditional: clears stale mask
            if (wm) { keptm |= wm; flags[r & 1] = 1; }  // same-value race benign
        }
        __syncthreads();
    }

    // ---- output straight from registers ----
    float* orow = out + (size_t)blockIdx.x * L;
    #pragma unroll
    for (int k = 0; k < C; k += 4) {
        float4 f;
        f.x = ((keptm >> (k + 0)) & 1u) ? xv[k + 0] : 0.0f;
        f.y = ((keptm >> (k + 1)) & 1u) ? xv[k + 1] : 0.0f;
        f.z = ((keptm >> (k + 2)) & 1u) ? xv[k + 2] : 0.0f;
        f.w = ((keptm >> (k + 3)) & 1u) ? xv[k + 3] : 0.0f;
        *reinterpret_cast<float4*>(orow + base + k) = f;
    }
}

extern "C" void kernel_launch(void* const* d_in, const int* in_sizes, int n_in,
                              void* d_out, int out_size, void* d_ws, size_t ws_size,
                              hipStream_t stream) {
    const float* in = (const float*)d_in[0];
    float* out = (float*)d_out;
    int rows = in_sizes[0] / L;   // 128
    extrema_nms_kernel<<<rows, NT, 0, stream>>>(in, out);
}

// Round 5
// 16.473 us; speedup vs baseline: 15.7206x; 1.2365x over previous
//
#include <hip/hip_runtime.h>

#define L 4096
#define NT 256
#define C 16                  // elements per thread (one chunk per thread)
#define MD 32                 // MIN_DIST
#define NC (NT + 4)           // padded chunk columns (2 each side)

typedef unsigned int u32;
typedef unsigned long long u64;

static __device__ __forceinline__ u32 umax(u32 a, u32 b) { return a > b ? a : b; }

// One block per row. Exact greedy NMS via iterative local-max peeling.
// u32 key = bits(|x|)+1 (0 = inactive). Ties in |x| resolved by asymmetric
// compares: left side beats on >=, right side beats on > — exactly the
// stable argsort(-|x|) (ascending index tie-break) order of the reference.
__global__ __launch_bounds__(NT) void extrema_nms_kernel(const float* __restrict__ in,
                                                         float* __restrict__ out) {
    __shared__ u32 pfxT[C][NC];   // pfxT[o][chunk] : prefix-max of chunk up to o
    __shared__ u32 sfxT[C][NC];   // sfxT[o][chunk] : suffix-max of chunk from o
    __shared__ u32 TA[NC];        // chunk max
    __shared__ u32 winm[NC];      // per-chunk winner mask (last round)
    __shared__ int flags[2];

    const int tid = threadIdx.x;
    const int cc = tid + 2;                      // padded chunk index
    const int base = tid * C;
    const float* xrow = in + (size_t)blockIdx.x * L;

    // ---- zero pads (columns 0,1 and NT+2,NT+3), written once ----
    if (tid < 64) {                              // 16 rows x 4 pad cols
        int o = tid >> 2, c = tid & 3;
        int col = (c & 1) + ((c >> 1) ? (NT + 2) : 0);
        pfxT[o][col] = 0;
        sfxT[o][col] = 0;
    }
    if (tid < 2) { TA[tid] = 0; TA[NT + 2 + tid] = 0; winm[tid] = 0; winm[NT + 2 + tid] = 0; }
    if (tid == 0) { flags[0] = 0; flags[1] = 0; }

    // ---- load own 16 x values + boundary neighbors ----
    float xv[C];
    #pragma unroll
    for (int k = 0; k < C; k += 4) {
        float4 f = *reinterpret_cast<const float4*>(xrow + base + k);
        xv[k] = f.x; xv[k + 1] = f.y; xv[k + 2] = f.z; xv[k + 3] = f.w;
    }
    float xl = (base > 0) ? xrow[base - 1] : 0.0f;
    float xr = (base + C < L) ? xrow[base + C] : 0.0f;

    // ---- extrema mask -> u32 keys in registers ----
    // right[i] = (i<L-1) && x[i+1] >  x[i]   (end pad => False at L-1)
    // left[i]  = (i==0)  || x[i]   <= x[i-1] (front pad => True at 0)
    u32 key[C];
    #pragma unroll
    for (int o = 0; o < C; ++o) {
        int i = base + o;
        float xi = xv[o];
        float xp = (o == 0) ? xl : xv[o - 1];
        float xn = (o == C - 1) ? xr : xv[o + 1];
        bool right = (i < L - 1) && (xn > xi);
        bool left  = (i == 0) || (xi <= xp);
        bool neg   = (xi <= 0.0f);
        bool ext = (right && left && neg) || (!right && !left && !neg);
        key[o] = ext ? ((__float_as_uint(xi) & 0x7fffffffu) + 1u) : 0u;
    }

    u32 keptm = 0;
    u32 sf[C + 1];               // own suffix-max, reused F->detect
    bool zeroed = false;         // LDS scans already hold zeros for my chunk

    // ---- peeling rounds: 2 barriers per round ----
    for (int r = 0; r < 200; ++r) {
        // ===== F phase: apply last round's winners, compute scans =====
        if (r > 0) {
            if (!flags[(r - 1) & 1]) break;      // uniform: fixpoint
            if (tid == 0) flags[r & 1] = 0;      // reset slot detect(r) will set
            // winner bits of chunks cc-2..cc+2 -> 80-bit window space
            u32 m0 = winm[cc - 2], m1 = winm[cc - 1], m2 = winm[cc];
            u32 m3 = winm[cc + 1], m4 = winm[cc + 2];
            u64 W0 = (u64)(m0 & 0xffffu) | ((u64)(m1 & 0xffffu) << 16)
                   | ((u64)(m2 & 0xffffu) << 32) | ((u64)(m3 & 0xffffu) << 48);
            u32 W1 = m4 & 0xffffu;
            // suppressed(o) iff any winner bit in [o, o+64]:
            //   from W0: any bit >= o  (o <= h0);  from W1: any bit <= o (l1 <= o)
            u32 supmask = 0;
            if (W0) { int h0 = 63 - __clzll(W0); supmask = (u32)((2ULL << h0) - 1ULL); }
            if (W1) { int l1 = __ffs(W1) - 1;    supmask |= ~((1u << l1) - 1u); }
            supmask &= 0xffffu;
            if (supmask) {
                #pragma unroll
                for (int o = 0; o < C; ++o)
                    if (supmask & (1u << o)) key[o] = 0;
            }
        }
        bool act = false;
        #pragma unroll
        for (int o = 0; o < C; ++o) act = act || (key[o] != 0);

        if (__ballot(act || !zeroed)) {          // wave-uniform skip when all dead
            u32 run = 0;
            #pragma unroll
            for (int o = 0; o < C; ++o) { run = umax(run, key[o]); pfxT[o][cc] = run; }
            TA[cc] = run;
            sf[C] = 0;
            #pragma unroll
            for (int o = C - 1; o >= 0; --o) { sf[o] = umax(sf[o + 1], key[o]); sfxT[o][cc] = sf[o]; }
            zeroed = !act;
        }
        __syncthreads();

        // ===== detect phase: winner = strict (tie-aware) max in own window =====
        if (__ballot(act)) {
            u32 tL = TA[cc - 1], tR = TA[cc + 1];
            u32 wm = 0;
            u32 pfrun = 0;
            #pragma unroll
            for (int o = 0; o < C; ++o) {
                u32 k = key[o];
                if (k) {
                    u32 bL = umax(umax(sfxT[o][cc - 2], tL), pfrun);  // beats me iff >= k
                    u32 bR = umax(umax(sf[o + 1], tR), pfxT[o][cc + 2]); // beats me iff > k
                    if (bL < k && bR <= k) wm |= (1u << o);
                }
                pfrun = umax(pfrun, k);
            }
            winm[cc] = wm;                        // also clears stale mask
            if (wm) { keptm |= wm; flags[r & 1] = 1; }  // same-value race benign
        } else {
            winm[cc] = 0;                         // clear stale mask
        }
        __syncthreads();
    }

    // ---- output straight from registers ----
    float* orow = out + (size_t)blockIdx.x * L;
    #pragma unroll
    for (int k = 0; k < C; k += 4) {
        float4 f;
        f.x = ((keptm >> (k + 0)) & 1u) ? xv[k + 0] : 0.0f;
        f.y = ((keptm >> (k + 1)) & 1u) ? xv[k + 1] : 0.0f;
        f.z = ((keptm >> (k + 2)) & 1u) ? xv[k + 2] : 0.0f;
        f.w = ((keptm >> (k + 3)) & 1u) ? xv[k + 3] : 0.0f;
        *reinterpret_cast<float4*>(orow + base + k) = f;
    }
}

extern "C" void kernel_launch(void* const* d_in, const int* in_sizes, int n_in,
                              void* d_out, int out_size, void* d_ws, size_t ws_size,
                              hipStream_t stream) {
    const float* in = (const float*)d_in[0];
    float* out = (float*)d_out;
    int rows = in_sizes[0] / L;   // 128
    extrema_nms_kernel<<<rows, NT, 0, stream>>>(in, out);
}

// Round 6
// 14.051 us; speedup vs baseline: 18.4307x; 1.1724x over previous
//
#include <hip/hip_runtime.h>

#define L 4096
#define NT 256
#define C 16                  // elements per thread (one chunk per thread)
#define MD 32                 // MIN_DIST
#define NC (NT + 4)           // chunk columns incl. 2 pads each side

typedef unsigned int u32;
typedef unsigned long long u64;

static __device__ __forceinline__ u32 umax(u32 a, u32 b) { return a > b ? a : b; }

// One block per row. Exact greedy NMS via iterative local-max peeling.
// u32 key = bits(|x|)+1 (0 = inactive). Only a chunk's FIRST argmax can win
// (window covers the whole 16-wide chunk; ties resolved left->=, right->).
// Keys live in registers + LDS mirror keyT (rewritten only on suppression).
__global__ __launch_bounds__(NT) void extrema_nms_kernel(const float* __restrict__ in,
                                                         float* __restrict__ out) {
    __shared__ u32 keyT[NC][C];      // [chunk][offset]; 64B rows -> b128 friendly
    __shared__ u32 winmF[2 * NC];    // winner masks, double-buffered by parity
    __shared__ int flagsF[2];

    const int tid = threadIdx.x;
    const int cc = tid + 2;                       // padded chunk index
    const int base = tid * C;
    const float* xrow = in + (size_t)blockIdx.x * L;

    // ---- pads / flags init ----
    if (tid < 64) {                               // 4 pad chunks x 16 words
        int c = tid >> 4, o = tid & 15;
        int col = (c & 1) + ((c >> 1) ? (NT + 2) : 0);
        keyT[col][o] = 0;
    }
    for (int w = tid; w < 2 * NC; w += NT) winmF[w] = 0;
    if (tid == 0) { flagsF[0] = 0; flagsF[1] = 0; }

    // ---- load own 16 x values + boundary neighbors ----
    float xv[C];
    #pragma unroll
    for (int k = 0; k < C; k += 4) {
        float4 f = *reinterpret_cast<const float4*>(xrow + base + k);
        xv[k] = f.x; xv[k + 1] = f.y; xv[k + 2] = f.z; xv[k + 3] = f.w;
    }
    float xl = (base > 0) ? xrow[base - 1] : 0.0f;
    float xr = (base + C < L) ? xrow[base + C] : 0.0f;

    // ---- extrema mask -> u32 keys ----
    // right[i] = (i<L-1) && x[i+1] >  x[i]; left[i] = (i==0) || x[i] <= x[i-1]
    u32 key[C];
    #pragma unroll
    for (int o = 0; o < C; ++o) {
        int i = base + o;
        float xi = xv[o];
        float xp = (o == 0) ? xl : xv[o - 1];
        float xn = (o == C - 1) ? xr : xv[o + 1];
        bool right = (i < L - 1) && (xn > xi);
        bool left  = (i == 0) || (xi <= xp);
        bool neg   = (xi <= 0.0f);
        bool ext = (right && left && neg) || (!right && !left && !neg);
        key[o] = ext ? ((__float_as_uint(xi) & 0x7fffffffu) + 1u) : 0u;
    }
    #pragma unroll
    for (int k = 0; k < C; k += 4)
        *reinterpret_cast<uint4*>(&keyT[cc][k]) =
            make_uint4(key[k], key[k + 1], key[k + 2], key[k + 3]);
    u32 run = 0, om = 0;                          // chunk max + FIRST argmax
    #pragma unroll
    for (int o = 0; o < C; ++o) if (key[o] > run) { run = key[o]; om = (u32)o; }

    u32 keptm = 0;
    __syncthreads();

    // ---- peeling rounds ----
    for (int r = 0; r < 200; ++r) {
        if (r > 0) {
            // ===== phase A: apply last round's winners =====
            const int pp = ((r - 1) & 1) * NC;
            int go = flagsF[(r - 1) & 1];
            u32 m0 = winmF[pp + cc - 2], m1 = winmF[pp + cc - 1], m2 = winmF[pp + cc];
            u32 m3 = winmF[pp + cc + 1], m4 = winmF[pp + cc + 2];
            if (!go) break;                        // uniform: fixpoint
            if (tid == 0) flagsF[r & 1] = 0;
            u64 W0 = (u64)(m0 & 0xffffu) | ((u64)(m1 & 0xffffu) << 16)
                   | ((u64)(m2 & 0xffffu) << 32) | ((u64)(m3 & 0xffffu) << 48);
            u32 W1 = m4 & 0xffffu;
            // suppressed(o) iff any winner bit in window [o, o+64] of the
            // 80-bit space [base-32, base+47]
            u32 supmask = 0;
            if (W0) { int h0 = 63 - __clzll(W0); supmask = (u32)((2ULL << h0) - 1ULL); }
            if (W1) { int l1 = __ffs(W1) - 1;    supmask |= ~((1u << l1) - 1u); }
            supmask &= 0xffffu;
            if (supmask) {
                #pragma unroll
                for (int o = 0; o < C; ++o) if ((supmask >> o) & 1u) key[o] = 0;
                #pragma unroll
                for (int k = 0; k < C; k += 4)
                    *reinterpret_cast<uint4*>(&keyT[cc][k]) =
                        make_uint4(key[k], key[k + 1], key[k + 2], key[k + 3]);
                run = 0; om = 0;
                #pragma unroll
                for (int o = 0; o < C; ++o) if (key[o] > run) { run = key[o]; om = (u32)o; }
            }
            __syncthreads();
        }
        // ===== phase B: detect (only the chunk argmax can win) =====
        if (run) {
            uint4 a0 = *reinterpret_cast<const uint4*>(&keyT[cc - 2][0]);
            uint4 a1 = *reinterpret_cast<const uint4*>(&keyT[cc - 2][4]);
            uint4 a2 = *reinterpret_cast<const uint4*>(&keyT[cc - 2][8]);
            uint4 a3 = *reinterpret_cast<const uint4*>(&keyT[cc - 2][12]);
            uint4 b0 = *reinterpret_cast<const uint4*>(&keyT[cc - 1][0]);
            uint4 b1 = *reinterpret_cast<const uint4*>(&keyT[cc - 1][4]);
            uint4 b2 = *reinterpret_cast<const uint4*>(&keyT[cc - 1][8]);
            uint4 b3 = *reinterpret_cast<const uint4*>(&keyT[cc - 1][12]);
            uint4 c0 = *reinterpret_cast<const uint4*>(&keyT[cc + 1][0]);
            uint4 c1 = *reinterpret_cast<const uint4*>(&keyT[cc + 1][4]);
            uint4 c2 = *reinterpret_cast<const uint4*>(&keyT[cc + 1][8]);
            uint4 c3 = *reinterpret_cast<const uint4*>(&keyT[cc + 1][12]);
            uint4 d0 = *reinterpret_cast<const uint4*>(&keyT[cc + 2][0]);
            uint4 d1 = *reinterpret_cast<const uint4*>(&keyT[cc + 2][4]);
            uint4 d2 = *reinterpret_cast<const uint4*>(&keyT[cc + 2][8]);
            uint4 d3 = *reinterpret_cast<const uint4*>(&keyT[cc + 2][12]);
            u32 A[C] = {a0.x,a0.y,a0.z,a0.w, a1.x,a1.y,a1.z,a1.w,
                        a2.x,a2.y,a2.z,a2.w, a3.x,a3.y,a3.z,a3.w};
            u32 B[C] = {b0.x,b0.y,b0.z,b0.w, b1.x,b1.y,b1.z,b1.w,
                        b2.x,b2.y,b2.z,b2.w, b3.x,b3.y,b3.z,b3.w};
            u32 Cc[C] = {c0.x,c0.y,c0.z,c0.w, c1.x,c1.y,c1.z,c1.w,
                         c2.x,c2.y,c2.z,c2.w, c3.x,c3.y,c3.z,c3.w};
            u32 D[C] = {d0.x,d0.y,d0.z,d0.w, d1.x,d1.y,d1.z,d1.w,
                        d2.x,d2.y,d2.z,d2.w, d3.x,d3.y,d3.z,d3.w};
            // left blocks on >=: suffix(>=om) of cc-2 + all of cc-1
            // right blocks on >: all of cc+1 + prefix(<=om) of cc+2
            u32 bL = 0, bR = 0;
            #pragma unroll
            for (int o = 0; o < C; ++o) {
                bL = umax(bL, ((u32)o >= om) ? A[o] : 0u);
                bL = umax(bL, B[o]);
                bR = umax(bR, Cc[o]);
                bR = umax(bR, ((u32)o <= om) ? D[o] : 0u);
            }
            bool win = (bL < run) && (bR <= run);
            u32 wm = win ? (1u << om) : 0u;
            winmF[(r & 1) * NC + cc] = wm;         // stale entries elsewhere are harmless
            if (wm) { keptm |= wm; flagsF[r & 1] = 1; }  // same-value races benign
        }
        __syncthreads();
    }

    // ---- output straight from registers ----
    float* orow = out + (size_t)blockIdx.x * L;
    #pragma unroll
    for (int k = 0; k < C; k += 4) {
        float4 f;
        f.x = ((keptm >> (k + 0)) & 1u) ? xv[k + 0] : 0.0f;
        f.y = ((keptm >> (k + 1)) & 1u) ? xv[k + 1] : 0.0f;
        f.z = ((keptm >> (k + 2)) & 1u) ? xv[k + 2] : 0.0f;
        f.w = ((keptm >> (k + 3)) & 1u) ? xv[k + 3] : 0.0f;
        *reinterpret_cast<float4*>(orow + base + k) = f;
    }
}

extern "C" void kernel_launch(void* const* d_in, const int* in_sizes, int n_in,
                              void* d_out, int out_size, void* d_ws, size_t ws_size,
                              hipStream_t stream) {
    const float* in = (const float*)d_in[0];
    float* out = (float*)d_out;
    int rows = in_sizes[0] / L;   // 128
    extrema_nms_kernel<<<rows, NT, 0, stream>>>(in, out);
}

// Round 7
// 12.309 us; speedup vs baseline: 21.0389x; 1.1415x over previous
//
#include <hip/hip_runtime.h>

#define L 4096
#define NT 256
#define C 16                  // elements per thread (one chunk per thread)
#define NC (NT + 4)           // chunk columns incl. 2 pads each side

typedef unsigned int u32;
typedef unsigned long long u64;

static __device__ __forceinline__ u32 umax(u32 a, u32 b) { return a > b ? a : b; }

// One block per row. Exact greedy NMS via iterative local-max peeling.
// u32 key = bits(|x|)+1 (0 = inactive). Only a chunk's FIRST argmax can win
// (its +-32 window covers the whole 16-wide chunk; ties: left blocks on >=,
// right blocks on >). Scan aggregates (pfx/sfx/TA) cached in LDS, rewritten
// only when a chunk's keys change -> detect is 4 scalar LDS reads.
__global__ __launch_bounds__(NT) void extrema_nms_kernel(const float* __restrict__ in,
                                                         float* __restrict__ out) {
    __shared__ u32 pfxT[C][NC];   // pfxT[o][chunk] = max key[0..o] of chunk
    __shared__ u32 sfxT[C][NC];   // sfxT[o][chunk] = max key[o..15] of chunk
    __shared__ u32 TA[NC];        // chunk max
    __shared__ u32 winmF[2 * NC]; // winner masks, double-buffered by parity
    __shared__ int flagsF[2];

    const int tid = threadIdx.x;
    const int cc = tid + 2;                       // padded chunk index
    const int base = tid * C;
    const float* xrow = in + (size_t)blockIdx.x * L;

    // ---- pads / flags init (written once) ----
    if (tid < 64) {                               // 16 rows x 4 pad cols
        int o = tid >> 2, c = tid & 3;
        int col = (c & 1) + ((c >> 1) ? (NT + 2) : 0);
        pfxT[o][col] = 0;
        sfxT[o][col] = 0;
    }
    if (tid < 2) { TA[tid] = 0; TA[NT + 2 + tid] = 0; }
    for (int w = tid; w < 2 * NC; w += NT) winmF[w] = 0;
    if (tid == 0) { flagsF[0] = 0; flagsF[1] = 0; }

    // ---- load own 16 x values + boundary neighbors ----
    float xv[C];
    #pragma unroll
    for (int k = 0; k < C; k += 4) {
        float4 f = *reinterpret_cast<const float4*>(xrow + base + k);
        xv[k] = f.x; xv[k + 1] = f.y; xv[k + 2] = f.z; xv[k + 3] = f.w;
    }
    float xl = (base > 0) ? xrow[base - 1] : 0.0f;
    float xr = (base + C < L) ? xrow[base + C] : 0.0f;

    // ---- extrema mask -> u32 keys ----
    // right[i] = (i<L-1) && x[i+1] >  x[i]; left[i] = (i==0) || x[i] <= x[i-1]
    u32 key[C];
    #pragma unroll
    for (int o = 0; o < C; ++o) {
        int i = base + o;
        float xi = xv[o];
        float xp = (o == 0) ? xl : xv[o - 1];
        float xn = (o == C - 1) ? xr : xv[o + 1];
        bool right = (i < L - 1) && (xn > xi);
        bool left  = (i == 0) || (xi <= xp);
        bool neg   = (xi <= 0.0f);
        bool ext = (right && left && neg) || (!right && !left && !neg);
        key[o] = ext ? ((__float_as_uint(xi) & 0x7fffffffu) + 1u) : 0u;
    }

    // ---- initial scans -> LDS; run/om in registers ----
    u32 run = 0, om = 0;
    {
        u32 p = 0;
        #pragma unroll
        for (int o = 0; o < C; ++o) { p = umax(p, key[o]); pfxT[o][cc] = p; }
        TA[cc] = p;
        u32 s = 0;
        #pragma unroll
        for (int o = C - 1; o >= 0; --o) { s = umax(s, key[o]); sfxT[o][cc] = s; }
        #pragma unroll
        for (int o = 0; o < C; ++o) if (key[o] > run) { run = key[o]; om = (u32)o; }
    }
    u32 keptm = 0;
    __syncthreads();

    // ---- peeling rounds: 2 barriers per round ----
    for (int r = 0; r < 200; ++r) {
        // ===== detect: only the chunk's first argmax can win =====
        if (run) {
            u32 bL = umax(sfxT[om][cc - 2], TA[cc - 1]);   // blocks iff >= run
            u32 bR = umax(TA[cc + 1], pfxT[om][cc + 2]);   // blocks iff >  run
            u32 wm = (bL < run && bR <= run) ? (1u << om) : 0u;
            winmF[(r & 1) * NC + cc] = wm;    // stale slots elsewhere: idempotent re-apply
            if (wm) { keptm |= wm; flagsF[r & 1] = 1; }    // same-value race benign
        }
        __syncthreads();

        // ===== apply winners (suppression) =====
        int go = flagsF[r & 1];
        const int pp = (r & 1) * NC;
        u32 m0 = winmF[pp + cc - 2], m1 = winmF[pp + cc - 1], m2 = winmF[pp + cc];
        u32 m3 = winmF[pp + cc + 1], m4 = winmF[pp + cc + 2];
        if (!go) break;                        // uniform: fixpoint reached
        if (tid == 0) flagsF[(r + 1) & 1] = 0; // 2 barriers since last read of that slot
        u64 W0 = (u64)(m0 & 0xffffu) | ((u64)(m1 & 0xffffu) << 16)
               | ((u64)(m2 & 0xffffu) << 32) | ((u64)(m3 & 0xffffu) << 48);
        u32 W1 = m4 & 0xffffu;
        // suppressed(o) iff any winner bit in window [o, o+64] of the 80-bit
        // space [base-32, base+47]
        u32 supmask = 0;
        if (W0) { int h0 = 63 - __clzll(W0); supmask = (u32)((2ULL << h0) - 1ULL); }
        if (W1) { int l1 = __ffs(W1) - 1;    supmask |= ~((1u << l1) - 1u); }
        supmask &= 0xffffu;
        if (run && supmask) {                  // keys change -> rewrite scans
            #pragma unroll
            for (int o = 0; o < C; ++o) if ((supmask >> o) & 1u) key[o] = 0;
            u32 p = 0;
            #pragma unroll
            for (int o = 0; o < C; ++o) { p = umax(p, key[o]); pfxT[o][cc] = p; }
            TA[cc] = p;
            u32 s = 0;
            #pragma unroll
            for (int o = C - 1; o >= 0; --o) { s = umax(s, key[o]); sfxT[o][cc] = s; }
            run = 0; om = 0;
            #pragma unroll
            for (int o = 0; o < C; ++o) if (key[o] > run) { run = key[o]; om = (u32)o; }
        }
        __syncthreads();
    }

    // ---- output straight from registers ----
    float* orow = out + (size_t)blockIdx.x * L;
    #pragma unroll
    for (int k = 0; k < C; k += 4) {
        float4 f;
        f.x = ((keptm >> (k + 0)) & 1u) ? xv[k + 0] : 0.0f;
        f.y = ((keptm >> (k + 1)) & 1u) ? xv[k + 1] : 0.0f;
        f.z = ((keptm >> (k + 2)) & 1u) ? xv[k + 2] : 0.0f;
        f.w = ((keptm >> (k + 3)) & 1u) ? xv[k + 3] : 0.0f;
        *reinterpret_cast<float4*>(orow + base + k) = f;
    }
}

extern "C" void kernel_launch(void* const* d_in, const int* in_sizes, int n_in,
                              void* d_out, int out_size, void* d_ws, size_t ws_size,
                              hipStream_t stream) {
    const float* in = (const float*)d_in[0];
    float* out = (float*)d_out;
    int rows = in_sizes[0] / L;   // 128
    extrema_nms_kernel<<<rows, NT, 0, stream>>>(in, out);
}

// Round 8
// 11.799 us; speedup vs baseline: 21.9479x; 1.0432x over previous
//
#include <hip/hip_runtime.h>

#define L 4096
#define NT 256
#define C 16                  // elements per thread (one chunk per thread)
#define NC (NT + 4)           // chunk rows incl. 2 pads each side
#define SS 20                 // scan row stride in words (80B, 16B-aligned)

typedef unsigned int u32;
typedef unsigned long long u64;

static __device__ __forceinline__ u32 umax(u32 a, u32 b) { return a > b ? a : b; }

// One block per row. Exact greedy NMS via iterative local-max peeling.
// u32 key = bits(|x|)+1 (0 = inactive). Only a chunk's FIRST argmax can win
// (chunk width 16 <= 33, so at most one winner/chunk/round — argmax-only is
// round-optimal). Ties: left blockers block on >=, right on > — exactly the
// stable argsort(-|x|) order. Scans cached in LDS row-major, rewritten only
// when a chunk's keys change (8 x ds_write_b128). TA folded into pfx[16].
__global__ __launch_bounds__(NT) void extrema_nms_kernel(const float* __restrict__ in,
                                                         float* __restrict__ out) {
    __shared__ u32 pfxS[NC * SS];  // [cc*SS + o]: o in 0..15 prefix-max, o=16 TA
    __shared__ u32 sfxS[NC * SS];  // [cc*SS + o]: o in 0..15 suffix-max
    __shared__ u32 winmF[2 * NC];  // winner masks, double-buffered by parity
    __shared__ int flagsF[2];

    const int tid = threadIdx.x;
    const int cc = tid + 2;
    const int base = tid * C;
    const float* xrow = in + (size_t)blockIdx.x * L;

    // ---- pads (written once, never again) ----
    if (tid < 4 * SS) {                       // rows 0,1,NT+2,NT+3
        int rsel = tid / SS;
        int row = (rsel & 1) + ((rsel >> 1) ? (NT + 2) : 0);
        int col = tid % SS;
        pfxS[row * SS + col] = 0;
        sfxS[row * SS + col] = 0;
    }
    if (tid < 4) {                            // winm pads, both parities
        int slot = (tid & 1) + ((tid >> 1) ? (NT + 2) : 0);
        winmF[slot] = 0;
        winmF[NC + slot] = 0;
    }
    if (tid == 0) { flagsF[0] = 0; flagsF[1] = 0; }

    // ---- load own 16 x values + boundary neighbors ----
    float xv[C];
    #pragma unroll
    for (int k = 0; k < C; k += 4) {
        float4 f = *reinterpret_cast<const float4*>(xrow + base + k);
        xv[k] = f.x; xv[k + 1] = f.y; xv[k + 2] = f.z; xv[k + 3] = f.w;
    }
    float xl = (base > 0) ? xrow[base - 1] : 0.0f;
    float xr = (base + C < L) ? xrow[base + C] : 0.0f;

    // ---- extrema mask -> u32 keys ----
    // right[i] = (i<L-1) && x[i+1] >  x[i]; left[i] = (i==0) || x[i] <= x[i-1]
    u32 key[C];
    #pragma unroll
    for (int o = 0; o < C; ++o) {
        int i = base + o;
        float xi = xv[o];
        float xp = (o == 0) ? xl : xv[o - 1];
        float xn = (o == C - 1) ? xr : xv[o + 1];
        bool right = (i < L - 1) && (xn > xi);
        bool left  = (i == 0) || (xi <= xp);
        bool neg   = (xi <= 0.0f);
        bool ext = (right && left && neg) || (!right && !left && !neg);
        key[o] = ext ? ((__float_as_uint(xi) & 0x7fffffffu) + 1u) : 0u;
    }

    // ---- initial scans -> LDS (b128), run/om in registers ----
    u32 run, om;
    {
        u32 pf[C], sf[C];
        u32 p = 0, nom = 0;
        #pragma unroll
        for (int o = 0; o < C; ++o) { u32 k = key[o]; if (k > p) { p = k; nom = (u32)o; } pf[o] = p; }
        u32 s = 0;
        #pragma unroll
        for (int o = C - 1; o >= 0; --o) { s = umax(s, key[o]); sf[o] = s; }
        u32* pr = &pfxS[cc * SS];
        u32* sr = &sfxS[cc * SS];
        #pragma unroll
        for (int k4 = 0; k4 < C; k4 += 4) {
            *reinterpret_cast<uint4*>(pr + k4) = make_uint4(pf[k4], pf[k4+1], pf[k4+2], pf[k4+3]);
            *reinterpret_cast<uint4*>(sr + k4) = make_uint4(sf[k4], sf[k4+1], sf[k4+2], sf[k4+3]);
        }
        pr[16] = p;                           // TA
        run = p; om = nom;
    }
    u32 keptm = 0;
    __syncthreads();

    // ---- peeling rounds: 2 barriers per round ----
    for (int r = 0; r < 200; ++r) {
        // ===== detect: only the chunk's first argmax can win =====
        u32 wm = 0;
        if (run) {
            u32 bL = umax(sfxS[(cc - 2) * SS + om], pfxS[(cc - 1) * SS + 16]); // >= blocks
            u32 bR = umax(pfxS[(cc + 1) * SS + 16], pfxS[(cc + 2) * SS + om]); // >  blocks
            if (bL < run && bR <= run) wm = 1u << om;
        }
        winmF[(r & 1) * NC + cc] = wm;        // unconditional: no stale masks ever
        if (wm) { keptm |= wm; flagsF[r & 1] = 1; }   // same-value race benign
        __syncthreads();

        // ===== apply winners =====
        int go = flagsF[r & 1];
        u32 m0 = 0, m1 = 0, m3 = 0, m4 = 0;
        if (run) {
            const int pp = (r & 1) * NC;
            m0 = winmF[pp + cc - 2]; m1 = winmF[pp + cc - 1];
            m3 = winmF[pp + cc + 1]; m4 = winmF[pp + cc + 2];
        }
        if (tid == 0) flagsF[(r + 1) & 1] = 0;        // safe: 2 barriers from last read
        if (!go) break;                                // uniform: fixpoint reached
        // winner bits of chunks cc-2..cc+2 in the 80-bit space [base-32, base+47];
        // suppressed(o) iff any winner bit in [o, o+64]
        u64 W0 = (u64)m0 | ((u64)m1 << 16) | ((u64)wm << 32) | ((u64)m3 << 48);
        u32 W1 = m4;
        u32 supmask = 0;
        if (W0) { int h0 = 63 - __clzll(W0); supmask = (h0 >= 15) ? 0xffffu : ((2u << h0) - 1u); }
        if (W1) { int l1 = __ffs((int)W1) - 1; supmask |= ~((1u << l1) - 1u); }
        supmask &= 0xffffu;
        if (run && supmask) {                 // keys change -> rewrite scans
            #pragma unroll
            for (int o = 0; o < C; ++o) key[o] = ((supmask >> o) & 1u) ? 0u : key[o];
            u32 pf[C], sf[C];
            u32 p = 0, nom = 0;
            #pragma unroll
            for (int o = 0; o < C; ++o) { u32 k = key[o]; if (k > p) { p = k; nom = (u32)o; } pf[o] = p; }
            u32 s = 0;
            #pragma unroll
            for (int o = C - 1; o >= 0; --o) { s = umax(s, key[o]); sf[o] = s; }
            u32* pr = &pfxS[cc * SS];
            u32* sr = &sfxS[cc * SS];
            #pragma unroll
            for (int k4 = 0; k4 < C; k4 += 4) {
                *reinterpret_cast<uint4*>(pr + k4) = make_uint4(pf[k4], pf[k4+1], pf[k4+2], pf[k4+3]);
                *reinterpret_cast<uint4*>(sr + k4) = make_uint4(sf[k4], sf[k4+1], sf[k4+2], sf[k4+3]);
            }
            pr[16] = p;
            run = p; om = nom;
        }
        __syncthreads();
    }

    // ---- output straight from registers ----
    float* orow = out + (size_t)blockIdx.x * L;
    #pragma unroll
    for (int k = 0; k < C; k += 4) {
        float4 f;
        f.x = ((keptm >> (k + 0)) & 1u) ? xv[k + 0] : 0.0f;
        f.y = ((keptm >> (k + 1)) & 1u) ? xv[k + 1] : 0.0f;
        f.z = ((keptm >> (k + 2)) & 1u) ? xv[k + 2] : 0.0f;
        f.w = ((keptm >> (k + 3)) & 1u) ? xv[k + 3] : 0.0f;
        *reinterpret_cast<float4*>(orow + base + k) = f;
    }
}

extern "C" void kernel_launch(void* const* d_in, const int* in_sizes, int n_in,
                              void* d_out, int out_size, void* d_ws, size_t ws_size,
                              hipStream_t stream) {
    const float* in = (const float*)d_in[0];
    float* out = (float*)d_out;
    int rows = in_sizes[0] / L;   // 128
    extrema_nms_kernel<<<rows, NT, 0, stream>>>(in, out);
}